// Round 1
// baseline (878.621 us; speedup 1.0000x reference)
//
#include <hip/hip_runtime.h>
#include <math.h>

#define LQ 4096
#define CQ 128
#define DI 256
#define DS 16
#define NCH 16   // chunks
#define TCH 256  // chunk length

__device__ __forceinline__ float siluf(float x) { return x / (1.f + expf(-x)); }
__device__ __forceinline__ float softplusf(float x) {
    return (x > 20.f) ? x : log1pf(expf(x));
}

// ---------------- K1: res = rgb+residual; u = LN(res); ef = LN(depth flipped) ----
__global__ __launch_bounds__(256)
void prep_kernel(const float* __restrict__ rgb, const float* __restrict__ resid,
                 const float* __restrict__ depth,
                 const float* __restrict__ sn1w, const float* __restrict__ sn1b,
                 const float* __restrict__ sn2w, const float* __restrict__ sn2b,
                 float* __restrict__ res_out, float* __restrict__ u, float* __restrict__ ef)
{
    int wid = threadIdx.x >> 6, lane = threadIdx.x & 63;
    int row = blockIdx.x * 4 + wid;            // b*4096 + l
    int b = row >> 12, l = row & 4095;
    int c0 = lane * 2;
    size_t base = (size_t)row * CQ + c0;

    float2 rg = *(const float2*)&rgb[base];
    float2 rs = *(const float2*)&resid[base];
    float2 r; r.x = rg.x + rs.x; r.y = rg.y + rs.y;
    *(float2*)&res_out[base] = r;

    float s = r.x + r.y, ss = r.x*r.x + r.y*r.y;
    #pragma unroll
    for (int m = 32; m; m >>= 1) { s += __shfl_xor(s, m); ss += __shfl_xor(ss, m); }
    float mu = s * (1.f/CQ);
    float var = ss * (1.f/CQ) - mu*mu;
    float ri = rsqrtf(var + 1e-5f);
    float2 w1 = *(const float2*)&sn1w[c0], b1 = *(const float2*)&sn1b[c0];
    float2 uo; uo.x = (r.x-mu)*ri*w1.x + b1.x; uo.y = (r.y-mu)*ri*w1.y + b1.y;
    *(float2*)&u[base] = uo;

    size_t dbase = ((size_t)b * LQ + (LQ-1 - l)) * CQ + c0;
    float2 dv = *(const float2*)&depth[dbase];
    float sd = dv.x + dv.y, ssd = dv.x*dv.x + dv.y*dv.y;
    #pragma unroll
    for (int m = 32; m; m >>= 1) { sd += __shfl_xor(sd, m); ssd += __shfl_xor(ssd, m); }
    float mud = sd * (1.f/CQ), vard = ssd * (1.f/CQ) - mud*mud;
    float rd = rsqrtf(vard + 1e-5f);
    float2 w2 = *(const float2*)&sn2w[c0], b2 = *(const float2*)&sn2b[c0];
    float2 eo; eo.x = (dv.x-mud)*rd*w2.x + b2.x; eo.y = (dv.y-mud)*rd*w2.y + b2.y;
    *(float2*)&ef[base] = eo;
}

// ---------------- generic row LN over last dim = 128 ----------------
__global__ __launch_bounds__(256)
void rowln_kernel(const float* __restrict__ in, const float* __restrict__ w,
                  const float* __restrict__ bvec, float* __restrict__ out, float eps)
{
    int wid = threadIdx.x >> 6, lane = threadIdx.x & 63;
    int row = blockIdx.x * 4 + wid;
    int c0 = lane * 2;
    size_t base = (size_t)row * CQ + c0;
    float2 v = *(const float2*)&in[base];
    float s = v.x + v.y, ss = v.x*v.x + v.y*v.y;
    #pragma unroll
    for (int m = 32; m; m >>= 1) { s += __shfl_xor(s, m); ss += __shfl_xor(ss, m); }
    float mu = s * (1.f/CQ), var = ss * (1.f/CQ) - mu*mu;
    float ri = rsqrtf(var + eps);
    float2 wv = *(const float2*)&w[c0], bv = *(const float2*)&bvec[c0];
    float2 o; o.x = (v.x-mu)*ri*wv.x + bv.x; o.y = (v.y-mu)*ri*wv.y + bv.y;
    *(float2*)&out[base] = o;
}

// ---------------- GEMM: out = A(MxK) @ W(NxK)^T, 64x64 tile, fp32 -------------
// EPI 0: split xz -> out0 = x half (n<256), out1 = silu(z half)
// EPI 1: out0[m*N+n] = v + aux[m*128+n]   (res add, N=128)
// EPI 2: out0[m*N+n] = v + aux[n]         (bias)
// EPI 3: transposed store with bias: out0[(b*128+n)*4096 + l] = v + aux[n]
template<int EPI>
__global__ __launch_bounds__(256)
void gemm_k(const float* __restrict__ A, const float* __restrict__ W,
            const float* __restrict__ aux,
            float* __restrict__ out0, float* __restrict__ out1,
            int M, int N, int K)
{
    __shared__ float As[16][64];
    __shared__ float Bs[16][64];
    int tid = threadIdx.x;
    int tx = tid & 15, ty = tid >> 4;
    int mBase = blockIdx.y * 64;
    int nBase = blockIdx.x * 64;
    int lr = tid >> 2;           // 0..63
    int lc = (tid & 3) << 2;     // 0,4,8,12
    float acc[4][4] = {};

    for (int k0 = 0; k0 < K; k0 += 16) {
        float4 av = *(const float4*)&A[(size_t)(mBase + lr) * K + k0 + lc];
        float4 bv = *(const float4*)&W[(size_t)(nBase + lr) * K + k0 + lc];
        __syncthreads();
        As[lc+0][lr] = av.x; As[lc+1][lr] = av.y; As[lc+2][lr] = av.z; As[lc+3][lr] = av.w;
        Bs[lc+0][lr] = bv.x; Bs[lc+1][lr] = bv.y; Bs[lc+2][lr] = bv.z; Bs[lc+3][lr] = bv.w;
        __syncthreads();
        #pragma unroll
        for (int kk = 0; kk < 16; ++kk) {
            float4 a4 = *(const float4*)&As[kk][ty*4];
            float4 b4 = *(const float4*)&Bs[kk][tx*4];
            float a[4] = {a4.x, a4.y, a4.z, a4.w};
            float b[4] = {b4.x, b4.y, b4.z, b4.w};
            #pragma unroll
            for (int i = 0; i < 4; ++i)
                #pragma unroll
                for (int j = 0; j < 4; ++j)
                    acc[i][j] = fmaf(a[i], b[j], acc[i][j]);
        }
    }

    #pragma unroll
    for (int i = 0; i < 4; ++i) {
        int m = mBase + ty*4 + i;
        #pragma unroll
        for (int j = 0; j < 4; ++j) {
            int n = nBase + tx*4 + j;
            float v = acc[i][j];
            if (EPI == 0) {
                if (n < DI) out0[(size_t)m*DI + n] = v;
                else        out1[(size_t)m*DI + (n - DI)] = siluf(v);
            } else if (EPI == 1) {
                out0[(size_t)m*N + n] = v + aux[(size_t)m*CQ + n];
            } else if (EPI == 2) {
                out0[(size_t)m*N + n] = v + aux[n];
            } else { // EPI == 3
                int b = m >> 12, l = m & 4095;
                out0[((size_t)(b*CQ + n) << 12) + l] = v + aux[n];
            }
        }
    }
}

// ---------------- K34: causal dwconv(k=4)+silu, x-proj (40), delta -----------
__global__ __launch_bounds__(64)
void convproj_kernel(const float* __restrict__ xh, const float* __restrict__ conv_w,
                     const float* __restrict__ conv_b, const float* __restrict__ xproj_w,
                     const float* __restrict__ dt_w, const float* __restrict__ dt_b,
                     float* __restrict__ xconv, float* __restrict__ delta,
                     float* __restrict__ BC)
{
    __shared__ float xr[DI];
    __shared__ float dts[8];
    int row = blockIdx.x;            // b*4096 + l
    int l = row & 4095;
    int tid = threadIdx.x;
    int d0 = tid * 4;

    float4 cb = *(const float4*)&conv_b[d0];
    float4 cw[4];
    #pragma unroll
    for (int j = 0; j < 4; ++j) cw[j] = *(const float4*)&conv_w[(d0 + j) * 4];
    float4 xv[4];
    #pragma unroll
    for (int i = 0; i < 4; ++i) {
        int t = l - 3 + i;
        if (t >= 0) xv[i] = *(const float4*)&xh[(size_t)(row - 3 + i) * DI + d0];
        else { xv[i].x = 0.f; xv[i].y = 0.f; xv[i].z = 0.f; xv[i].w = 0.f; }
    }
    float4 outv;
    #pragma unroll
    for (int j = 0; j < 4; ++j) {
        float a = (&cb.x)[j];
        #pragma unroll
        for (int i = 0; i < 4; ++i) a = fmaf((&xv[i].x)[j], (&cw[j].x)[i], a);
        a = siluf(a);
        (&outv.x)[j] = a;
        xr[d0 + j] = a;
    }
    *(float4*)&xconv[(size_t)row * DI + d0] = outv;
    __syncthreads();

    if (tid < 40) {
        const float* wp = &xproj_w[tid * DI];
        float a = 0.f;
        #pragma unroll 4
        for (int c = 0; c < DI; c += 4) {
            float4 wv = *(const float4*)&wp[c];
            a = fmaf(xr[c+0], wv.x, a); a = fmaf(xr[c+1], wv.y, a);
            a = fmaf(xr[c+2], wv.z, a); a = fmaf(xr[c+3], wv.w, a);
        }
        if (tid >= 8) BC[(size_t)row * 32 + (tid - 8)] = a;
        else dts[tid] = a;
    }
    __syncthreads();

    float dv[8];
    #pragma unroll
    for (int r = 0; r < 8; ++r) dv[r] = dts[r];
    #pragma unroll
    for (int q = 0; q < 4; ++q) {
        int d = tid + q * 64;
        float4 wa = *(const float4*)&dt_w[d*8];
        float4 wb = *(const float4*)&dt_w[d*8 + 4];
        float a = dt_b[d];
        a = fmaf(dv[0], wa.x, a); a = fmaf(dv[1], wa.y, a);
        a = fmaf(dv[2], wa.z, a); a = fmaf(dv[3], wa.w, a);
        a = fmaf(dv[4], wb.x, a); a = fmaf(dv[5], wb.y, a);
        a = fmaf(dv[6], wb.z, a); a = fmaf(dv[7], wb.w, a);
        delta[(size_t)row * DI + d] = softplusf(a);
    }
}

// ---------------- scan phase 1: per-chunk affine summary ----------------
__global__ __launch_bounds__(256)
void scan1_kernel(const float* __restrict__ delta, const float* __restrict__ xc,
                  const float* __restrict__ BC, const float* __restrict__ A_log,
                  float* __restrict__ Ap, float* __restrict__ Bsum)
{
    int gid = blockIdx.x * 256 + threadIdx.x;
    int s  = gid & 15;
    int d  = (gid >> 4) & 255;
    int ci = (gid >> 12) & 15;
    int b  = gid >> 16;
    float Ads = -expf(A_log[d * DS + s]);
    int row0 = b * LQ + ci * TCH;
    const float* pd = delta + (size_t)row0 * DI + d;
    const float* px = xc    + (size_t)row0 * DI + d;
    const float* pb = BC    + (size_t)row0 * 32 + s;
    float ap = 1.f, bs = 0.f;
    for (int t = 0; t < TCH; ++t) {
        float dt = *pd, x = *px, Bv = *pb;
        float a = expf(dt * Ads);
        ap *= a;
        bs = fmaf(a, bs, dt * x * Bv);
        pd += DI; px += DI; pb += 32;
    }
    size_t idx = ((((size_t)b*256 + d) * NCH + ci) << 4) + s;
    Ap[idx] = ap; Bsum[idx] = bs;
}

// ---------------- scan phase 2: chunk-boundary states ----------------
__global__ __launch_bounds__(256)
void scan2_kernel(const float* __restrict__ Ap, const float* __restrict__ Bsum,
                  float* __restrict__ Hs)
{
    int gid = blockIdx.x * 256 + threadIdx.x;   // 16384
    int s = gid & 15, d = (gid >> 4) & 255, b = gid >> 12;
    float h = 0.f;
    size_t base = (((size_t)b*256 + d) * NCH) * 16 + s;
    #pragma unroll
    for (int ci = 0; ci < NCH; ++ci) {
        Hs[base + ci*16] = h;
        h = fmaf(Ap[base + ci*16], h, Bsum[base + ci*16]);
    }
}

// ---------------- scan phase 3: replay + y, gate, (flip-)store ----------------
template<int ACCUM>
__global__ __launch_bounds__(256)
void scan3_kernel(const float* __restrict__ delta, const float* __restrict__ xc,
                  const float* __restrict__ BC, const float* __restrict__ A_log,
                  const float* __restrict__ Dp, const float* __restrict__ zs,
                  const float* __restrict__ Hs, float* __restrict__ Y)
{
    int gid = blockIdx.x * 256 + threadIdx.x;
    int s  = gid & 15;
    int d  = (gid >> 4) & 255;
    int ci = (gid >> 12) & 15;
    int b  = gid >> 16;
    float Ads = -expf(A_log[d * DS + s]);
    float Dd = Dp[d];
    size_t idx = ((((size_t)b*256 + d) * NCH + ci) << 4) + s;
    float h = Hs[idx];
    int t0 = ci * TCH;
    int row0 = b * LQ + t0;
    const float* pd = delta + (size_t)row0 * DI + d;
    const float* px = xc    + (size_t)row0 * DI + d;
    const float* pb = BC    + (size_t)row0 * 32 + s;
    const float* pc = pb + 16;
    for (int t = 0; t < TCH; ++t) {
        float dt = *pd, x = *px, Bv = *pb, Cv = *pc;
        float a = expf(dt * Ads);
        h = fmaf(a, h, dt * x * Bv);
        float p = h * Cv;
        p += __shfl_xor(p, 1); p += __shfl_xor(p, 2);
        p += __shfl_xor(p, 4); p += __shfl_xor(p, 8);
        if (s == 0) {
            int tg = t0 + t;
            float zv = zs[((size_t)b * LQ + tg) * DI + d];
            float val = (p + x * Dd) * zv;
            size_t orow = ACCUM ? ((size_t)b * LQ + (LQ-1 - tg)) : ((size_t)b * LQ + tg);
            if (ACCUM) Y[orow * DI + d] += val;
            else       Y[orow * DI + d] = val;
        }
        pd += DI; px += DI; pb += 32; pc += 32;
    }
}

// ---------------- grouped 3x3 conv (groups=128, 2 in / 2 out per group) -------
__global__ __launch_bounds__(256)
void dwconv3x3_kernel(const float* __restrict__ h1, const float* __restrict__ w,
                      const float* __restrict__ bias, float* __restrict__ h2)
{
    int gid = blockIdx.x * 256 + threadIdx.x;     // b*4096*128 + l*128 + g
    int g = gid & 127;
    int l = (gid >> 7) & 4095;
    int b = gid >> 19;
    int y = l >> 6, x = l & 63;
    int o0 = g * 2;
    float acc0 = bias[o0], acc1 = bias[o0+1];
    const float* w0 = &w[(size_t)o0 * 18];
    const float* w1 = &w[(size_t)(o0+1) * 18];
    #pragma unroll
    for (int ky = 0; ky < 3; ++ky) {
        int yy = y + ky - 1;
        if (yy < 0 || yy > 63) continue;
        #pragma unroll
        for (int kx = 0; kx < 3; ++kx) {
            int xx = x + kx - 1;
            if (xx < 0 || xx > 63) continue;
            float2 v = *(const float2*)&h1[(((size_t)b*LQ) + yy*64 + xx) * DI + o0];
            int wi = ky*3 + kx;
            acc0 = fmaf(v.x, w0[wi], acc0); acc0 = fmaf(v.y, w0[9+wi], acc0);
            acc1 = fmaf(v.x, w1[wi], acc1); acc1 = fmaf(v.y, w1[9+wi], acc1);
        }
    }
    float2 o; o.x = acc0; o.y = acc1;
    *(float2*)&h2[((size_t)b*LQ + l) * DI + o0] = o;
}

// =============================== launch ===============================
extern "C" void kernel_launch(void* const* d_in, const int* in_sizes, int n_in,
                              void* d_out, int out_size, void* d_ws, size_t ws_size,
                              hipStream_t stream)
{
    const float* rgb   = (const float*)d_in[0];
    const float* resid = (const float*)d_in[1];
    const float* depth = (const float*)d_in[2];
    const float* sn1w  = (const float*)d_in[4];
    const float* sn1b  = (const float*)d_in[5];
    const float* sn2w  = (const float*)d_in[6];
    const float* sn2b  = (const float*)d_in[7];
    const float* cnw   = (const float*)d_in[8];
    const float* cnb   = (const float*)d_in[9];
    const float* out_w = (const float*)d_in[10];
    const float* f1w   = (const float*)d_in[11];
    const float* f1b   = (const float*)d_in[12];
    const float* f2w   = (const float*)d_in[13];
    const float* f2b   = (const float*)d_in[14];
    const float* f3w   = (const float*)d_in[15];
    const float* f3b   = (const float*)d_in[16];

    float* out = (float*)d_out;
    float* res_out = out + 2097152;           // output 1
    float* ws = (float*)d_ws;

    float* u   = ws;                          // 2M floats
    float* ef  = ws + 2097152;                // 2M
    float* Y   = ws + 4194304;                // 4M
    float* xh  = ws + 8388608;                // 4M
    float* zs  = ws + 12582912;               // 4M
    float* xc  = ws + 16777216;               // 4M
    float* de  = ws + 20971520;               // 4M
    float* BC  = ws + 25165824;               // 0.5M
    float* Ap  = ws + 25690112;               // 256K
    float* Bsm = ws + 25952256;               // 256K
    float* Hs  = ws + 26214400;               // 256K
    float* sp = u;     // tail reuse
    float* t1 = ef;
    float* h1 = xh;
    float* h2 = zs;

    prep_kernel<<<4096, 256, 0, stream>>>(rgb, resid, depth, sn1w, sn1b, sn2w, sn2b,
                                          res_out, u, ef);

    for (int br = 0; br < 2; ++br) {
        int o = 17 + br * 8;
        const float* in_w    = (const float*)d_in[o+0];
        const float* conv_w  = (const float*)d_in[o+1];
        const float* conv_b  = (const float*)d_in[o+2];
        const float* xproj_w = (const float*)d_in[o+3];
        const float* dt_w    = (const float*)d_in[o+4];
        const float* dt_b    = (const float*)d_in[o+5];
        const float* A_log   = (const float*)d_in[o+6];
        const float* Dp      = (const float*)d_in[o+7];
        const float* src = (br == 0) ? u : ef;

        gemm_k<0><<<dim3(8, 256), 256, 0, stream>>>(src, in_w, nullptr, xh, zs,
                                                    16384, 512, 128);
        convproj_kernel<<<16384, 64, 0, stream>>>(xh, conv_w, conv_b, xproj_w,
                                                  dt_w, dt_b, xc, de, BC);
        scan1_kernel<<<1024, 256, 0, stream>>>(de, xc, BC, A_log, Ap, Bsm);
        scan2_kernel<<<64, 256, 0, stream>>>(Ap, Bsm, Hs);
        if (br == 0)
            scan3_kernel<0><<<1024, 256, 0, stream>>>(de, xc, BC, A_log, Dp, zs, Hs, Y);
        else
            scan3_kernel<1><<<1024, 256, 0, stream>>>(de, xc, BC, A_log, Dp, zs, Hs, Y);
    }

    // gf = Y @ out_w^T + res  -> sp (B,L,128)
    gemm_k<1><<<dim3(2, 256), 256, 0, stream>>>(Y, out_w, res_out, sp, nullptr,
                                                16384, 128, 256);
    // channel LN (eps 1e-6)
    rowln_kernel<<<4096, 256, 0, stream>>>(sp, cnw, cnb, t1, 1e-6f);
    // f1: 1x1 conv 128->256
    gemm_k<2><<<dim3(4, 256), 256, 0, stream>>>(t1, f1w, f1b, h1, nullptr,
                                                16384, 256, 128);
    // f2: grouped 3x3
    dwconv3x3_kernel<<<8192, 256, 0, stream>>>(h1, f2w, f2b, h2);
    // f3: 1x1 conv 256->128, transposed store into d_out (B,C,H,W)
    gemm_k<3><<<dim3(2, 256), 256, 0, stream>>>(h2, f3w, f3b, out, nullptr,
                                                16384, 128, 256);
}